// Round 1
// baseline (1095.762 us; speedup 1.0000x reference)
//
#include <hip/hip_runtime.h>
#include <math.h>

#define BATCH 16384
#define NCAT 24

// log(1e-30f), log(16)
#define L30F  (-69.07755279f)
#define LOGKF (2.7725887f)

__device__ __forceinline__ float lae(float a, float b) {
    float m = fmaxf(a, b);
    return m + logf(expf(a - m) + expf(b - m));
}

// ---------------------------------------------------------------- schedules
// sched layout: [0..999]=LOG_A, [1000..]=LOG_1M_A, [2000..]=LOG_CA,
// [3000..]=LOG_1M_CA, [4000..]=SQRT_AC, [5000..]=SQRT_1M_AC
__global__ __launch_bounds__(256) void sched_kernel(float* __restrict__ sched,
                                                    double* __restrict__ acc) {
    __shared__ double la_s[1000];
    __shared__ double lca_s[1000];
    const double PI = 3.14159265358979323846;
    int tid = threadIdx.x;
    for (int i = tid; i < 1000; i += 256) {
        double u0 = ((double)i / 1000.0 + 0.008) / 1.008 * PI * 0.5;
        double u1 = ((double)(i + 1) / 1000.0 + 0.008) / 1.008 * PI * 0.5;
        double c0 = cos(u0), c1 = cos(u1);
        double ab0 = c0 * c0, ab1 = c1 * c1;
        double beta = 1.0 - ab1 / ab0;
        if (beta > 0.999) beta = 0.999;
        la_s[i] = log(1.0 - beta);
    }
    __syncthreads();
    if (tid == 0) {
        double run = 0.0;
        for (int i = 0; i < 1000; ++i) { run += la_s[i]; lca_s[i] = run; }
        *acc = 0.0;
    }
    __syncthreads();
    for (int i = tid; i < 1000; i += 256) {
        double la = la_s[i], lca = lca_s[i];
        sched[i]        = (float)la;
        sched[1000 + i] = (float)log(1.0 - exp(la) + 1e-40);
        sched[2000 + i] = (float)lca;
        sched[3000 + i] = (float)log(1.0 - exp(lca) + 1e-40);
        sched[4000 + i] = (float)sqrt(exp(lca));
        sched[5000 + i] = (float)sqrt(1.0 - exp(lca));
    }
}

// ------------------------------------------------- timestep embedding table
__global__ __launch_bounds__(256) void emb0_kernel(float* __restrict__ E0) {
    int gid = blockIdx.x * 256 + threadIdx.x;
    if (gid >= 1000 * 1024) return;
    int t = gid >> 10, j = gid & 1023;
    int jj = (j < 512) ? j : j - 512;
    float freq = expf(-logf(10000.0f) * (float)jj / 512.0f);
    float arg = (float)t * freq;
    E0[gid] = (j < 512) ? cosf(arg) : sinf(arg);
}

// ---------------------------------------------- column sums of proj_w[16:400]
__global__ __launch_bounds__(256) void catsum_kernel(const float* __restrict__ proj_w,
                                                     float* __restrict__ catsum) {
    int j = blockIdx.x * 256 + threadIdx.x;
    if (j >= 1024) return;
    float s = 0.0f;
    for (int r = 16; r < 400; ++r) s += proj_w[(size_t)r * 1024 + j];
    catsum[j] = s;
}

// ---------------------------------------------------------------- fp32 GEMM
// C[M,N] = epi(A[M,K] @ B[K,N] + bias). EPI: 0=bias, 1=silu, 2=relu
template <int EPI>
__global__ __launch_bounds__(256) void gemm_f32(const float* __restrict__ A,
                                                const float* __restrict__ Bw,
                                                const float* __restrict__ bias,
                                                float* __restrict__ C,
                                                int M, int N, int Kd) {
    __shared__ __align__(16) float As[16][64];  // [k][m]
    __shared__ __align__(16) float Bs[16][64];  // [k][n]
    const int bm = blockIdx.y * 64;
    const int bn = blockIdx.x * 64;
    const int tid = threadIdx.x;
    const int tx = tid & 15, ty = tid >> 4;
    const int arow = tid >> 2;
    const int akq  = (tid & 3) << 2;
    const int bkr = tid >> 4;
    const int bnq = (tid & 15) << 2;
    float acc[4][4] = {};
    for (int k0 = 0; k0 < Kd; k0 += 16) {
        float4 av = make_float4(0.f, 0.f, 0.f, 0.f);
        int m = bm + arow;
        if (m < M) av = *(const float4*)(A + (size_t)m * Kd + k0 + akq);
        float4 bv = make_float4(0.f, 0.f, 0.f, 0.f);
        int n = bn + bnq;
        const float* bp = Bw + (size_t)(k0 + bkr) * N + n;
        if (n + 3 < N) {
            bv = *(const float4*)bp;
        } else if (n < N) {
            bv.x = bp[0];
            if (n + 1 < N) bv.y = bp[1];
            if (n + 2 < N) bv.z = bp[2];
        }
        As[akq + 0][arow] = av.x;
        As[akq + 1][arow] = av.y;
        As[akq + 2][arow] = av.z;
        As[akq + 3][arow] = av.w;
        *(float4*)&Bs[bkr][bnq] = bv;
        __syncthreads();
#pragma unroll
        for (int kk = 0; kk < 16; ++kk) {
            float4 a4 = *(const float4*)&As[kk][ty << 2];
            float4 b4 = *(const float4*)&Bs[kk][tx << 2];
            float a[4] = {a4.x, a4.y, a4.z, a4.w};
            float b[4] = {b4.x, b4.y, b4.z, b4.w};
#pragma unroll
            for (int i = 0; i < 4; ++i)
#pragma unroll
                for (int j = 0; j < 4; ++j)
                    acc[i][j] = fmaf(a[i], b[j], acc[i][j]);
        }
        __syncthreads();
    }
#pragma unroll
    for (int i = 0; i < 4; ++i) {
        int m = bm + (ty << 2) + i;
        if (m >= M) continue;
#pragma unroll
        for (int j = 0; j < 4; ++j) {
            int n = bn + (tx << 2) + j;
            if (n >= N) continue;
            float v = acc[i][j] + bias[n];
            if (EPI == 1) v = v / (1.0f + expf(-v));
            if (EPI == 2) v = fmaxf(v, 0.0f);
            C[(size_t)m * N + n] = v;
        }
    }
}

// --------------------------------------------------- per-row prep: h + samp
__global__ __launch_bounds__(256) void row_prep(
    const float* __restrict__ x_num, const int* __restrict__ x_cat,
    const int* __restrict__ t_in, const float* __restrict__ noise,
    const float* __restrict__ gum, const float* __restrict__ proj_w,
    const float* __restrict__ proj_b, const float* __restrict__ sched,
    const float* __restrict__ EMB, const float* __restrict__ catsum,
    float* __restrict__ h, int* __restrict__ hot) {
    __shared__ float xnt[16][16];
    __shared__ int sh_hot[16][24];
    __shared__ int sh_t[16];
    const int b0 = blockIdx.x * 16;
    const int tid = threadIdx.x;
    const float* LOG_CA = sched + 2000;
    const float* LOG_1M_CA = sched + 3000;
    const float* SQ_AC = sched + 4000;
    const float* SQ_1M = sched + 5000;
    if (tid < 16) sh_t[tid] = t_in[b0 + tid];
    __syncthreads();
    {
        int r = tid >> 4, i = tid & 15;
        int t = sh_t[r];
        xnt[r][i] = SQ_AC[t] * x_num[(size_t)(b0 + r) * 16 + i] +
                    SQ_1M[t] * noise[(size_t)(b0 + r) * 16 + i];
    }
    for (int task = tid; task < 16 * 24; task += 256) {
        int r = task / 24, c = task - r * 24;
        int t = sh_t[r];
        int xc = x_cat[(size_t)(b0 + r) * 24 + c];
        float l1 = LOG_1M_CA[t] - LOGKF;
        float lca = LOG_CA[t];
        float vh = lae(lca, l1);
        float vo = lae(L30F + lca, l1);
        const float* gu = gum + (size_t)(b0 + r) * 384 + c * 16;
        float best = -3.0e38f;
        int bi = 0;
#pragma unroll
        for (int k = 0; k < 16; ++k) {
            float g = -logf(-logf(gu[k] + 1e-30f) + 1e-30f);
            float v = g + ((k == xc) ? vh : vo);
            if (v > best) { best = v; bi = k; }
        }
        sh_hot[r][c] = bi;
        hot[(size_t)(b0 + r) * 24 + c] = bi;
    }
    __syncthreads();
    for (int jj = 0; jj < 4; ++jj) {
        int j = (jj << 8) + tid;
        float wn[16];
#pragma unroll
        for (int i = 0; i < 16; ++i) wn[i] = proj_w[(size_t)i * 1024 + j];
        float base = proj_b[j] + L30F * catsum[j];
        for (int r = 0; r < 16; ++r) {
            float acc = base + EMB[(size_t)sh_t[r] * 1024 + j];
            float gs = 0.0f;
#pragma unroll
            for (int c = 0; c < 24; ++c)
                gs += proj_w[(size_t)(16 + (c << 4) + sh_hot[r][c]) * 1024 + j];
            acc -= L30F * gs;
#pragma unroll
            for (int i = 0; i < 16; ++i) acc = fmaf(xnt[r][i], wn[i], acc);
            h[(size_t)(b0 + r) * 1024 + j] = acc;
        }
    }
}

// ------------------------------------------------------------- reductions
__device__ __forceinline__ void block_reduce_add(double contrib, double* acc_out) {
    for (int off = 32; off > 0; off >>= 1)
        contrib += __shfl_down(contrib, off);
    __shared__ double wsum[4];
    int lane = threadIdx.x & 63, wv = threadIdx.x >> 6;
    if (lane == 0) wsum[wv] = contrib;
    __syncthreads();
    if (threadIdx.x == 0)
        atomicAdd(acc_out, wsum[0] + wsum[1] + wsum[2] + wsum[3]);
}

// one thread per (row, category)
__global__ __launch_bounds__(256) void loss_cat(
    const int* __restrict__ x_cat, const int* __restrict__ t_in,
    const int* __restrict__ hot, const float* __restrict__ MO,
    const float* __restrict__ sched, double* __restrict__ acc_out) {
    int gid = blockIdx.x * 256 + threadIdx.x;
    double contrib = 0.0;
    if (gid < BATCH * NCAT) {
        int b = gid / NCAT, c = gid - b * NCAT;
        int t = t_in[b];
        int xc = x_cat[b * NCAT + c];
        int s = hot[b * NCAT + c];
        const float* LOG_A = sched;
        const float* LOG_1M_A = sched + 1000;
        const float* LOG_CA = sched + 2000;
        const float* LOG_1M_CA = sched + 3000;
        const float* oc = MO + (size_t)b * 400 + 16 + c * 16;
        float ocv[16];
        float mx = -3e38f;
#pragma unroll
        for (int k = 0; k < 16; ++k) { ocv[k] = oc[k]; mx = fmaxf(mx, ocv[k]); }
        float sm = 0.0f;
#pragma unroll
        for (int k = 0; k < 16; ++k) sm += expf(ocv[k] - mx);
        float lse = mx + logf(sm);
        int tm1 = (t > 0) ? t - 1 : 0;
        float lca1 = LOG_CA[tm1];
        float l1m1 = LOG_1M_CA[tm1] - LOGKF;
        float la = LOG_A[t];
        float l1a = LOG_1M_A[t] - LOGKF;
        float qh = lae(la, l1a);
        float qo = lae(L30F + la, l1a);
        float levh = (t == 0) ? 0.0f : lae(lca1, l1m1);
        float levo = (t == 0) ? L30F : lae(L30F + lca1, l1m1);
        float un[16], ut[16];
        float mu = -3e38f, mt2 = -3e38f;
#pragma unroll
        for (int k = 0; k < 16; ++k) {
            float lxh = ocv[k] - lse;
            float lev = (t == 0) ? lxh : lae(lxh + lca1, l1m1);
            float q = (k == s) ? qh : qo;
            un[k] = lev + q;
            ut[k] = ((k == xc) ? levh : levo) + q;
            mu = fmaxf(mu, un[k]);
            mt2 = fmaxf(mt2, ut[k]);
        }
        float su = 0.0f, st = 0.0f;
#pragma unroll
        for (int k = 0; k < 16; ++k) { su += expf(un[k] - mu); st += expf(ut[k] - mt2); }
        float lsu = mu + logf(su), lst = mt2 + logf(st);
        float kl = 0.0f, dn = 0.0f;
#pragma unroll
        for (int k = 0; k < 16; ++k) {
            float lmp = un[k] - lsu;
            float ltp = ut[k] - lst;
            kl += expf(ltp) * (ltp - lmp);
            dn -= ((k == xc) ? 1.0f : 1e-30f) * lmp;
        }
        float Lt = (t == 0) ? dn : kl;
        float lcaT = LOG_CA[999];
        float l1mT = LOG_1M_CA[999] - LOGKF;
        float ph = lae(lcaT, l1mT);
        float po = lae(L30F + lcaT, l1mT);
        float prior = expf(ph) * (ph + LOGKF) + 15.0f * expf(po) * (po + LOGKF);
        contrib = (double)(Lt + prior) / (24.0 * BATCH);
    }
    block_reduce_add(contrib, acc_out);
}

// one thread per (row, numeric-dim)
__global__ __launch_bounds__(256) void loss_gauss(
    const float* __restrict__ noise, const float* __restrict__ MO,
    double* __restrict__ acc_out) {
    int gid = blockIdx.x * 256 + threadIdx.x;
    double contrib = 0.0;
    if (gid < BATCH * 16) {
        int b = gid >> 4, i = gid & 15;
        float d = noise[gid] - MO[(size_t)b * 400 + i];
        contrib = (double)(d * d) / (16.0 * BATCH);
    }
    block_reduce_add(contrib, acc_out);
}

__global__ void finalize_kernel(const double* __restrict__ acc, float* __restrict__ out) {
    out[0] = (float)(*acc);
}

extern "C" void kernel_launch(void* const* d_in, const int* in_sizes, int n_in,
                              void* d_out, int out_size, void* d_ws, size_t ws_size,
                              hipStream_t stream) {
    const float* x_num  = (const float*)d_in[0];
    const int*   x_cat  = (const int*)d_in[1];
    const int*   t_in   = (const int*)d_in[2];
    const float* noise  = (const float*)d_in[3];
    const float* gum    = (const float*)d_in[4];
    const float* te_w1  = (const float*)d_in[5];
    const float* te_b1  = (const float*)d_in[6];
    const float* te_w2  = (const float*)d_in[7];
    const float* te_b2  = (const float*)d_in[8];
    const float* proj_w = (const float*)d_in[9];
    const float* proj_b = (const float*)d_in[10];
    const float* mlp_w1 = (const float*)d_in[11];
    const float* mlp_b1 = (const float*)d_in[12];
    const float* mlp_w2 = (const float*)d_in[13];
    const float* mlp_b2 = (const float*)d_in[14];
    float* out = (float*)d_out;

    char* w = (char*)d_ws;
    size_t off = 0;
    auto alloc = [&](size_t bytes) {
        void* p = w + off;
        off += (bytes + 1023) & ~(size_t)1023;
        return p;
    };
    double* acc   = (double*)alloc(1024);
    float* sched  = (float*)alloc(6 * 1000 * 4);
    int*   hot    = (int*)alloc((size_t)BATCH * 24 * 4);
    float* catsum = (float*)alloc(1024 * 4);
    float* E0     = (float*)alloc((size_t)1000 * 1024 * 4);
    float* E1     = (float*)alloc((size_t)1000 * 1024 * 4);
    float* h      = (float*)alloc((size_t)BATCH * 1024 * 4);
    float* R      = (float*)alloc((size_t)BATCH * 1024 * 4);
    float* EMB    = E0;  // E0 dead after GEMM1
    float* MO     = h;   // h dead after GEMM3 (MO is 16384x400 <= h bytes)

    sched_kernel<<<1, 256, 0, stream>>>(sched, acc);
    emb0_kernel<<<4000, 256, 0, stream>>>(E0);
    catsum_kernel<<<4, 256, 0, stream>>>(proj_w, catsum);
    // E1 = silu(E0 @ te_w1 + te_b1)
    gemm_f32<1><<<dim3(16, 16), 256, 0, stream>>>(E0, te_w1, te_b1, E1, 1000, 1024, 1024);
    // EMB = E1 @ te_w2 + te_b2   (EMB aliases E0)
    gemm_f32<0><<<dim3(16, 16), 256, 0, stream>>>(E1, te_w2, te_b2, EMB, 1000, 1024, 1024);
    row_prep<<<BATCH / 16, 256, 0, stream>>>(x_num, x_cat, t_in, noise, gum,
                                             proj_w, proj_b, sched, EMB, catsum, h, hot);
    // R = relu(h @ mlp_w1 + mlp_b1)
    gemm_f32<2><<<dim3(16, 256), 256, 0, stream>>>(h, mlp_w1, mlp_b1, R, BATCH, 1024, 1024);
    // MO = R @ mlp_w2 + mlp_b2   (MO aliases h)
    gemm_f32<0><<<dim3(7, 256), 256, 0, stream>>>(R, mlp_w2, mlp_b2, MO, BATCH, 400, 1024);
    loss_cat<<<(BATCH * NCAT) / 256, 256, 0, stream>>>(x_cat, t_in, hot, MO, sched, acc);
    loss_gauss<<<(BATCH * 16) / 256, 256, 0, stream>>>(noise, MO, acc);
    finalize_kernel<<<1, 1, 0, stream>>>(acc, out);
}

// Round 2
// 506.337 us; speedup vs baseline: 2.1641x; 2.1641x over previous
//
#include <hip/hip_runtime.h>
#include <hip/hip_bf16.h>
#include <math.h>

#define BATCH 16384
#define NCAT 24

// log(1e-30f), log(16)
#define L30F  (-69.07755279f)
#define LOGKF (2.7725887f)

typedef __attribute__((ext_vector_type(8))) short short8;
typedef __attribute__((ext_vector_type(4))) float f32x4;

__device__ __forceinline__ float lae(float a, float b) {
    float m = fmaxf(a, b);
    return m + logf(expf(a - m) + expf(b - m));
}

__device__ __forceinline__ void glds16(const void* g, void* l) {
    __builtin_amdgcn_global_load_lds((const __attribute__((address_space(1))) void*)g,
                                     (__attribute__((address_space(3))) void*)l,
                                     16, 0, 0);
}

// ---------------------------------------------------------------- schedules
// sched layout: [0..999]=LOG_A, [1000..]=LOG_1M_A, [2000..]=LOG_CA,
// [3000..]=LOG_1M_CA, [4000..]=SQRT_AC, [5000..]=SQRT_1M_AC
__global__ __launch_bounds__(256) void sched_kernel(float* __restrict__ sched,
                                                    double* __restrict__ acc) {
    __shared__ double la_s[1000];
    __shared__ double lca_s[1000];
    const double PI = 3.14159265358979323846;
    int tid = threadIdx.x;
    for (int i = tid; i < 1000; i += 256) {
        double u0 = ((double)i / 1000.0 + 0.008) / 1.008 * PI * 0.5;
        double u1 = ((double)(i + 1) / 1000.0 + 0.008) / 1.008 * PI * 0.5;
        double c0 = cos(u0), c1 = cos(u1);
        double ab0 = c0 * c0, ab1 = c1 * c1;
        double beta = 1.0 - ab1 / ab0;
        if (beta > 0.999) beta = 0.999;
        la_s[i] = log(1.0 - beta);
    }
    __syncthreads();
    if (tid == 0) {
        double run = 0.0;
        for (int i = 0; i < 1000; ++i) { run += la_s[i]; lca_s[i] = run; }
        *acc = 0.0;
    }
    __syncthreads();
    for (int i = tid; i < 1000; i += 256) {
        double la = la_s[i], lca = lca_s[i];
        sched[i]        = (float)la;
        sched[1000 + i] = (float)log(1.0 - exp(la) + 1e-40);
        sched[2000 + i] = (float)lca;
        sched[3000 + i] = (float)log(1.0 - exp(lca) + 1e-40);
        sched[4000 + i] = (float)sqrt(exp(lca));
        sched[5000 + i] = (float)sqrt(1.0 - exp(lca));
    }
}

// ------------------------------------------------- timestep embedding table (bf16)
__global__ __launch_bounds__(256) void emb0_kernel(__hip_bfloat16* __restrict__ E0) {
    int gid = blockIdx.x * 256 + threadIdx.x;
    if (gid >= 1000 * 1024) return;
    int t = gid >> 10, j = gid & 1023;
    int jj = (j < 512) ? j : j - 512;
    float freq = expf(-logf(10000.0f) * (float)jj / 512.0f);
    float arg = (float)t * freq;
    E0[gid] = __float2bfloat16((j < 512) ? cosf(arg) : sinf(arg));
}

// ---------------------------------------------- column sums of proj_w[16:400]
__global__ __launch_bounds__(256) void catsum_kernel(const float* __restrict__ proj_w,
                                                     float* __restrict__ catsum) {
    int j = blockIdx.x * 256 + threadIdx.x;
    if (j >= 1024) return;
    float s = 0.0f;
    for (int r = 16; r < 400; ++r) s += proj_w[(size_t)r * 1024 + j];
    catsum[j] = s;
}

// ------------------------------------- weight transpose + f32->bf16 convert
// in:  W  [K x Nw] row-major f32
// out: Wt [Npad x K] row-major bf16, rows >= Nw zero-filled
__global__ __launch_bounds__(256) void wtrans_kernel(const float* __restrict__ W,
                                                     __hip_bfloat16* __restrict__ Wt,
                                                     int K, int Nw, int Npad) {
    __shared__ float t[32][33];
    int n0 = blockIdx.x * 32, k0 = blockIdx.y * 32;
    int c = threadIdx.x & 31, r8 = threadIdx.x >> 5;  // r8: 0..7
#pragma unroll
    for (int i = 0; i < 32; i += 8) {
        int k = k0 + r8 + i, n = n0 + c;
        t[r8 + i][c] = (n < Nw && k < K) ? W[(size_t)k * Nw + n] : 0.0f;
    }
    __syncthreads();
#pragma unroll
    for (int i = 0; i < 32; i += 8) {
        int n = n0 + r8 + i, k = k0 + c;
        if (n < Npad && k < K) Wt[(size_t)n * K + k] = __float2bfloat16(t[c][r8 + i]);
    }
}

// ------------------------------------------------------------ bf16 MFMA GEMM
// C[M,Nreal] = epi(A[M,Kd] @ Bt^T + bias), A row-major bf16, Bt is [Npad x Kd]
// bf16 (N-major, i.e. B transposed). 128x128 block tile, BK=32, 4 waves (2x2),
// each wave 4x4 x (16x16x32) MFMA. global_load_lds width=16 staging.
// EPI: 0 = f32 store, 1 = silu + bf16 store, 2 = relu + bf16 store
template <int EPI>
__global__ __launch_bounds__(256) void gemm_mfma(
    const __hip_bfloat16* __restrict__ A, const __hip_bfloat16* __restrict__ Bt,
    const float* __restrict__ bias, void* __restrict__ Cout,
    int M, int Kd, int Nreal, int Cstride) {
    __shared__ __hip_bfloat16 As[128 * 32];
    __shared__ __hip_bfloat16 Bs[128 * 32];
    const int tid = threadIdx.x;
    const int lane = tid & 63, wave = tid >> 6;
    const int wm = wave >> 1, wn = wave & 1;
    const int m0 = blockIdx.y * 128, n0 = blockIdx.x * 128;
    const int l4 = lane >> 2;          // row within a 16-row staging chunk
    const int lc = (lane & 3) * 8;     // bf16-element k-offset within row

    // staging instruction indices for this wave: 2*wave, 2*wave+1 (of 8)
    const __hip_bfloat16* ag[2];
    const __hip_bfloat16* bg[2];
    void* lA[2];
    void* lB[2];
#pragma unroll
    for (int ii = 0; ii < 2; ++ii) {
        int inst = wave * 2 + ii;
        int ra = m0 + inst * 16 + l4;
        if (ra > M - 1) ra = M - 1;           // clamp (stores are guarded)
        int rb = n0 + inst * 16 + l4;         // Bt rows are padded to tile
        ag[ii] = A + (size_t)ra * Kd + lc;
        bg[ii] = Bt + (size_t)rb * Kd + lc;
        lA[ii] = (char*)As + inst * 1024;
        lB[ii] = (char*)Bs + inst * 1024;
    }

    f32x4 acc[4][4] = {};
    const int q8 = (lane >> 4) * 8;
    const int l15 = lane & 15;

    for (int k0 = 0; k0 < Kd; k0 += 32) {
        glds16(ag[0] + k0, lA[0]);
        glds16(ag[1] + k0, lA[1]);
        glds16(bg[0] + k0, lB[0]);
        glds16(bg[1] + k0, lB[1]);
        __syncthreads();
        short8 af[4], bfr[4];
#pragma unroll
        for (int i = 0; i < 4; ++i) {
            af[i]  = *(const short8*)(As + (size_t)(wm * 64 + i * 16 + l15) * 32 + q8);
            bfr[i] = *(const short8*)(Bs + (size_t)(wn * 64 + i * 16 + l15) * 32 + q8);
        }
#pragma unroll
        for (int i = 0; i < 4; ++i)
#pragma unroll
            for (int j = 0; j < 4; ++j)
                acc[i][j] = __builtin_amdgcn_mfma_f32_16x16x32_bf16(
                    af[i], bfr[j], acc[i][j], 0, 0, 0);
        __syncthreads();
    }

#pragma unroll
    for (int i = 0; i < 4; ++i) {
        int mbase = m0 + wm * 64 + i * 16 + (lane >> 4) * 4;
#pragma unroll
        for (int j = 0; j < 4; ++j) {
            int n = n0 + wn * 64 + j * 16 + l15;
            if (n >= Nreal) continue;
            float bv = bias[n];
#pragma unroll
            for (int r = 0; r < 4; ++r) {
                int m = mbase + r;
                if (m >= M) continue;
                float v = acc[i][j][r] + bv;
                if (EPI == 1) v = v / (1.0f + expf(-v));
                if (EPI == 2) v = fmaxf(v, 0.0f);
                if (EPI == 0)
                    ((float*)Cout)[(size_t)m * Cstride + n] = v;
                else
                    ((__hip_bfloat16*)Cout)[(size_t)m * Cstride + n] = __float2bfloat16(v);
            }
        }
    }
}

// --------------------------------------------------- per-row prep: h + samp
__global__ __launch_bounds__(256) void row_prep(
    const float* __restrict__ x_num, const int* __restrict__ x_cat,
    const int* __restrict__ t_in, const float* __restrict__ noise,
    const float* __restrict__ gum, const float* __restrict__ proj_w,
    const float* __restrict__ proj_b, const float* __restrict__ sched,
    const float* __restrict__ EMB, const float* __restrict__ catsum,
    __hip_bfloat16* __restrict__ h, int* __restrict__ hot) {
    __shared__ float xnt[16][16];
    __shared__ int sh_hot[16][24];
    __shared__ int sh_t[16];
    const int b0 = blockIdx.x * 16;
    const int tid = threadIdx.x;
    const float* LOG_CA = sched + 2000;
    const float* LOG_1M_CA = sched + 3000;
    const float* SQ_AC = sched + 4000;
    const float* SQ_1M = sched + 5000;
    if (tid < 16) sh_t[tid] = t_in[b0 + tid];
    __syncthreads();
    {
        int r = tid >> 4, i = tid & 15;
        int t = sh_t[r];
        xnt[r][i] = SQ_AC[t] * x_num[(size_t)(b0 + r) * 16 + i] +
                    SQ_1M[t] * noise[(size_t)(b0 + r) * 16 + i];
    }
    for (int task = tid; task < 16 * 24; task += 256) {
        int r = task / 24, c = task - r * 24;
        int t = sh_t[r];
        int xc = x_cat[(size_t)(b0 + r) * 24 + c];
        float l1 = LOG_1M_CA[t] - LOGKF;
        float lca = LOG_CA[t];
        float vh = lae(lca, l1);
        float vo = lae(L30F + lca, l1);
        const float* gu = gum + (size_t)(b0 + r) * 384 + c * 16;
        float best = -3.0e38f;
        int bi = 0;
#pragma unroll
        for (int k = 0; k < 16; ++k) {
            float g = -logf(-logf(gu[k] + 1e-30f) + 1e-30f);
            float v = g + ((k == xc) ? vh : vo);
            if (v > best) { best = v; bi = k; }
        }
        sh_hot[r][c] = bi;
        hot[(size_t)(b0 + r) * 24 + c] = bi;
    }
    __syncthreads();
    for (int jj = 0; jj < 4; ++jj) {
        int j = (jj << 8) + tid;
        float wn[16];
#pragma unroll
        for (int i = 0; i < 16; ++i) wn[i] = proj_w[(size_t)i * 1024 + j];
        float base = proj_b[j] + L30F * catsum[j];
        for (int r = 0; r < 16; ++r) {
            float acc = base + EMB[(size_t)sh_t[r] * 1024 + j];
            float gs = 0.0f;
#pragma unroll
            for (int c = 0; c < 24; ++c)
                gs += proj_w[(size_t)(16 + (c << 4) + sh_hot[r][c]) * 1024 + j];
            acc -= L30F * gs;
#pragma unroll
            for (int i = 0; i < 16; ++i) acc = fmaf(xnt[r][i], wn[i], acc);
            h[(size_t)(b0 + r) * 1024 + j] = __float2bfloat16(acc);
        }
    }
}

// ------------------------------------------------------------- reductions
__device__ __forceinline__ void block_reduce_add(double contrib, double* acc_out) {
    for (int off = 32; off > 0; off >>= 1)
        contrib += __shfl_down(contrib, off);
    __shared__ double wsum[4];
    int lane = threadIdx.x & 63, wv = threadIdx.x >> 6;
    if (lane == 0) wsum[wv] = contrib;
    __syncthreads();
    if (threadIdx.x == 0)
        atomicAdd(acc_out, wsum[0] + wsum[1] + wsum[2] + wsum[3]);
}

// one thread per (row, category)
__global__ __launch_bounds__(256) void loss_cat(
    const int* __restrict__ x_cat, const int* __restrict__ t_in,
    const int* __restrict__ hot, const float* __restrict__ MO,
    const float* __restrict__ sched, double* __restrict__ acc_out) {
    int gid = blockIdx.x * 256 + threadIdx.x;
    double contrib = 0.0;
    if (gid < BATCH * NCAT) {
        int b = gid / NCAT, c = gid - b * NCAT;
        int t = t_in[b];
        int xc = x_cat[b * NCAT + c];
        int s = hot[b * NCAT + c];
        const float* LOG_A = sched;
        const float* LOG_1M_A = sched + 1000;
        const float* LOG_CA = sched + 2000;
        const float* LOG_1M_CA = sched + 3000;
        const float* oc = MO + (size_t)b * 400 + 16 + c * 16;
        float ocv[16];
        float mx = -3e38f;
#pragma unroll
        for (int k = 0; k < 16; ++k) { ocv[k] = oc[k]; mx = fmaxf(mx, ocv[k]); }
        float sm = 0.0f;
#pragma unroll
        for (int k = 0; k < 16; ++k) sm += expf(ocv[k] - mx);
        float lse = mx + logf(sm);
        int tm1 = (t > 0) ? t - 1 : 0;
        float lca1 = LOG_CA[tm1];
        float l1m1 = LOG_1M_CA[tm1] - LOGKF;
        float la = LOG_A[t];
        float l1a = LOG_1M_A[t] - LOGKF;
        float qh = lae(la, l1a);
        float qo = lae(L30F + la, l1a);
        float levh = (t == 0) ? 0.0f : lae(lca1, l1m1);
        float levo = (t == 0) ? L30F : lae(L30F + lca1, l1m1);
        float un[16], ut[16];
        float mu = -3e38f, mt2 = -3e38f;
#pragma unroll
        for (int k = 0; k < 16; ++k) {
            float lxh = ocv[k] - lse;
            float lev = (t == 0) ? lxh : lae(lxh + lca1, l1m1);
            float q = (k == s) ? qh : qo;
            un[k] = lev + q;
            ut[k] = ((k == xc) ? levh : levo) + q;
            mu = fmaxf(mu, un[k]);
            mt2 = fmaxf(mt2, ut[k]);
        }
        float su = 0.0f, st = 0.0f;
#pragma unroll
        for (int k = 0; k < 16; ++k) { su += expf(un[k] - mu); st += expf(ut[k] - mt2); }
        float lsu = mu + logf(su), lst = mt2 + logf(st);
        float kl = 0.0f, dn = 0.0f;
#pragma unroll
        for (int k = 0; k < 16; ++k) {
            float lmp = un[k] - lsu;
            float ltp = ut[k] - lst;
            kl += expf(ltp) * (ltp - lmp);
            dn -= ((k == xc) ? 1.0f : 1e-30f) * lmp;
        }
        float Lt = (t == 0) ? dn : kl;
        float lcaT = LOG_CA[999];
        float l1mT = LOG_1M_CA[999] - LOGKF;
        float ph = lae(lcaT, l1mT);
        float po = lae(L30F + lcaT, l1mT);
        float prior = expf(ph) * (ph + LOGKF) + 15.0f * expf(po) * (po + LOGKF);
        contrib = (double)(Lt + prior) / (24.0 * BATCH);
    }
    block_reduce_add(contrib, acc_out);
}

// one thread per (row, numeric-dim)
__global__ __launch_bounds__(256) void loss_gauss(
    const float* __restrict__ noise, const float* __restrict__ MO,
    double* __restrict__ acc_out) {
    int gid = blockIdx.x * 256 + threadIdx.x;
    double contrib = 0.0;
    if (gid < BATCH * 16) {
        int b = gid >> 4, i = gid & 15;
        float d = noise[gid] - MO[(size_t)b * 400 + i];
        contrib = (double)(d * d) / (16.0 * BATCH);
    }
    block_reduce_add(contrib, acc_out);
}

__global__ void finalize_kernel(const double* __restrict__ acc, float* __restrict__ out) {
    out[0] = (float)(*acc);
}

extern "C" void kernel_launch(void* const* d_in, const int* in_sizes, int n_in,
                              void* d_out, int out_size, void* d_ws, size_t ws_size,
                              hipStream_t stream) {
    const float* x_num  = (const float*)d_in[0];
    const int*   x_cat  = (const int*)d_in[1];
    const int*   t_in   = (const int*)d_in[2];
    const float* noise  = (const float*)d_in[3];
    const float* gum    = (const float*)d_in[4];
    const float* te_w1  = (const float*)d_in[5];
    const float* te_b1  = (const float*)d_in[6];
    const float* te_w2  = (const float*)d_in[7];
    const float* te_b2  = (const float*)d_in[8];
    const float* proj_w = (const float*)d_in[9];
    const float* proj_b = (const float*)d_in[10];
    const float* mlp_w1 = (const float*)d_in[11];
    const float* mlp_b1 = (const float*)d_in[12];
    const float* mlp_w2 = (const float*)d_in[13];
    const float* mlp_b2 = (const float*)d_in[14];
    float* out = (float*)d_out;

    char* w = (char*)d_ws;
    size_t off = 0;
    auto alloc = [&](size_t bytes) {
        void* p = w + off;
        off += (bytes + 1023) & ~(size_t)1023;
        return p;
    };
    double* acc   = (double*)alloc(1024);
    float* sched  = (float*)alloc(6 * 1000 * 4);
    int*   hot    = (int*)alloc((size_t)BATCH * 24 * 4);
    float* catsum = (float*)alloc(1024 * 4);
    __hip_bfloat16* E0    = (__hip_bfloat16*)alloc((size_t)1000 * 1024 * 2);
    __hip_bfloat16* E1    = (__hip_bfloat16*)alloc((size_t)1000 * 1024 * 2);
    float* EMB            = (float*)alloc((size_t)1000 * 1024 * 4);
    __hip_bfloat16* tw1t  = (__hip_bfloat16*)alloc((size_t)1024 * 1024 * 2);
    __hip_bfloat16* tw2t  = (__hip_bfloat16*)alloc((size_t)1024 * 1024 * 2);
    __hip_bfloat16* w1t   = (__hip_bfloat16*)alloc((size_t)1024 * 1024 * 2);
    __hip_bfloat16* w2t   = (__hip_bfloat16*)alloc((size_t)512 * 1024 * 2);
    __hip_bfloat16* h     = (__hip_bfloat16*)alloc((size_t)BATCH * 1024 * 2);
    __hip_bfloat16* R     = (__hip_bfloat16*)alloc((size_t)BATCH * 1024 * 2);
    float* MO             = (float*)alloc((size_t)BATCH * 400 * 4);

    sched_kernel<<<1, 256, 0, stream>>>(sched, acc);
    emb0_kernel<<<4000, 256, 0, stream>>>(E0);
    catsum_kernel<<<4, 256, 0, stream>>>(proj_w, catsum);
    // weight transposes + bf16 convert
    wtrans_kernel<<<dim3(32, 32), 256, 0, stream>>>(te_w1, tw1t, 1024, 1024, 1024);
    wtrans_kernel<<<dim3(32, 32), 256, 0, stream>>>(te_w2, tw2t, 1024, 1024, 1024);
    wtrans_kernel<<<dim3(32, 32), 256, 0, stream>>>(mlp_w1, w1t, 1024, 1024, 1024);
    wtrans_kernel<<<dim3(16, 32), 256, 0, stream>>>(mlp_w2, w2t, 1024, 400, 512);
    // E1 = silu(E0 @ te_w1 + te_b1)   [bf16 out]
    gemm_mfma<1><<<dim3(8, 8), 256, 0, stream>>>(E0, tw1t, te_b1, E1, 1000, 1024, 1024, 1024);
    // EMB = E1 @ te_w2 + te_b2        [f32 out]
    gemm_mfma<0><<<dim3(8, 8), 256, 0, stream>>>(E1, tw2t, te_b2, EMB, 1000, 1024, 1024, 1024);
    row_prep<<<BATCH / 16, 256, 0, stream>>>(x_num, x_cat, t_in, noise, gum,
                                             proj_w, proj_b, sched, EMB, catsum, h, hot);
    // R = relu(h @ mlp_w1 + mlp_b1)   [bf16 out]
    gemm_mfma<2><<<dim3(8, 128), 256, 0, stream>>>(h, w1t, mlp_b1, R, BATCH, 1024, 1024, 1024);
    // MO = R @ mlp_w2 + mlp_b2        [f32 out, N=400]
    gemm_mfma<0><<<dim3(4, 128), 256, 0, stream>>>(R, w2t, mlp_b2, MO, BATCH, 1024, 400, 400);
    loss_cat<<<(BATCH * NCAT) / 256, 256, 0, stream>>>(x_cat, t_in, hot, MO, sched, acc);
    loss_gauss<<<(BATCH * 16) / 256, 256, 0, stream>>>(noise, MO, acc);
    finalize_kernel<<<1, 1, 0, stream>>>(acc, out);
}

// Round 3
// 467.665 us; speedup vs baseline: 2.3430x; 1.0827x over previous
//
#include <hip/hip_runtime.h>
#include <hip/hip_bf16.h>
#include <math.h>

#define BATCH 16384
#define NCAT 24

// log(1e-30f), log(16)
#define L30F  (-69.07755279f)
#define LOGKF (2.7725887f)

typedef __attribute__((ext_vector_type(8))) short short8;
typedef __attribute__((ext_vector_type(4))) float f32x4;

__device__ __forceinline__ float lae(float a, float b) {
    float m = fmaxf(a, b);
    return m + logf(expf(a - m) + expf(b - m));
}

__device__ __forceinline__ void glds16(const void* g, void* l) {
    __builtin_amdgcn_global_load_lds((const __attribute__((address_space(1))) void*)g,
                                     (__attribute__((address_space(3))) void*)l,
                                     16, 0, 0);
}

// ---------------------------------------------------------------- schedules
// sched layout: [0..999]=LOG_A, [1000..]=LOG_1M_A, [2000..]=LOG_CA,
// [3000..]=LOG_1M_CA, [4000..]=SQRT_AC, [5000..]=SQRT_1M_AC
__global__ __launch_bounds__(256) void sched_kernel(float* __restrict__ sched,
                                                    double* __restrict__ acc) {
    __shared__ double la_s[1000];
    __shared__ double lca_s[1000];
    const double PI = 3.14159265358979323846;
    int tid = threadIdx.x;
    for (int i = tid; i < 1000; i += 256) {
        double u0 = ((double)i / 1000.0 + 0.008) / 1.008 * PI * 0.5;
        double u1 = ((double)(i + 1) / 1000.0 + 0.008) / 1.008 * PI * 0.5;
        double c0 = cos(u0), c1 = cos(u1);
        double ab0 = c0 * c0, ab1 = c1 * c1;
        double beta = 1.0 - ab1 / ab0;
        if (beta > 0.999) beta = 0.999;
        la_s[i] = log(1.0 - beta);
    }
    __syncthreads();
    if (tid == 0) {
        double run = 0.0;
        for (int i = 0; i < 1000; ++i) { run += la_s[i]; lca_s[i] = run; }
        *acc = 0.0;
    }
    __syncthreads();
    for (int i = tid; i < 1000; i += 256) {
        double la = la_s[i], lca = lca_s[i];
        sched[i]        = (float)la;
        sched[1000 + i] = (float)log(1.0 - exp(la) + 1e-40);
        sched[2000 + i] = (float)lca;
        sched[3000 + i] = (float)log(1.0 - exp(lca) + 1e-40);
        sched[4000 + i] = (float)sqrt(exp(lca));
        sched[5000 + i] = (float)sqrt(1.0 - exp(lca));
    }
}

// ------------------------------------------------- timestep embedding table (bf16)
__global__ __launch_bounds__(256) void emb0_kernel(__hip_bfloat16* __restrict__ E0) {
    int gid = blockIdx.x * 256 + threadIdx.x;
    if (gid >= 1000 * 1024) return;
    int t = gid >> 10, j = gid & 1023;
    int jj = (j < 512) ? j : j - 512;
    float freq = expf(-logf(10000.0f) * (float)jj / 512.0f);
    float arg = (float)t * freq;
    E0[gid] = __float2bfloat16((j < 512) ? cosf(arg) : sinf(arg));
}

// ------------------------- colconst[j] = proj_b[j] + L30F * sum proj_w[16:400][j]
__global__ __launch_bounds__(256) void colconst_kernel(const float* __restrict__ proj_w,
                                                       const float* __restrict__ proj_b,
                                                       float* __restrict__ colconst) {
    int j = blockIdx.x * 256 + threadIdx.x;
    if (j >= 1024) return;
    float s = 0.0f;
    for (int r = 16; r < 400; ++r) s += proj_w[(size_t)r * 1024 + j];
    colconst[j] = proj_b[j] + L30F * s;
}

// ------------------------------------- weight transpose + f32->bf16 convert
// in:  W  [K x Nw] row-major f32
// out: Wt [Npad x Kpad] row-major bf16, zero-filled where n >= Nw or k >= K
__global__ __launch_bounds__(256) void wtrans_kernel(const float* __restrict__ W,
                                                     __hip_bfloat16* __restrict__ Wt,
                                                     int K, int Kpad, int Nw, int Npad) {
    __shared__ float t[32][33];
    int n0 = blockIdx.x * 32, k0 = blockIdx.y * 32;
    int c = threadIdx.x & 31, r8 = threadIdx.x >> 5;  // r8: 0..7
#pragma unroll
    for (int i = 0; i < 32; i += 8) {
        int k = k0 + r8 + i, n = n0 + c;
        t[r8 + i][c] = (n < Nw && k < K) ? W[(size_t)k * Nw + n] : 0.0f;
    }
    __syncthreads();
#pragma unroll
    for (int i = 0; i < 32; i += 8) {
        int n = n0 + r8 + i, k = k0 + c;
        if (n < Npad && k < Kpad) Wt[(size_t)n * Kpad + k] = __float2bfloat16(t[c][r8 + i]);
    }
}

// ------------------------------------------------------------ bf16 MFMA GEMM
// C[M,Nreal] = epi(A[M,Kd] @ Bt^T + bias), A row-major bf16, Bt is [Npad x Kd]
// bf16 (N-major). 128x128 block tile, BK=32, 4 waves (2x2), each wave 4x4 of
// 16x16x32 MFMA. global_load_lds width=16 staging.
// EPI: 0 = f32 store, 1 = silu + bf16, 2 = relu + bf16,
//      3 = (+ rowbias[tidx[m]][n]) + bf16
template <int EPI>
__global__ __launch_bounds__(256) void gemm_mfma(
    const __hip_bfloat16* __restrict__ A, const __hip_bfloat16* __restrict__ Bt,
    const float* __restrict__ bias, void* __restrict__ Cout,
    int M, int Kd, int Nreal, int Cstride,
    const int* __restrict__ tidx, const float* __restrict__ rowbias) {
    __shared__ __hip_bfloat16 As[128 * 32];
    __shared__ __hip_bfloat16 Bs[128 * 32];
    const int tid = threadIdx.x;
    const int lane = tid & 63, wave = tid >> 6;
    const int wm = wave >> 1, wn = wave & 1;
    const int m0 = blockIdx.y * 128, n0 = blockIdx.x * 128;
    const int l4 = lane >> 2;          // row within a 16-row staging chunk
    const int lc = (lane & 3) * 8;     // bf16-element k-offset within row

    const __hip_bfloat16* ag[2];
    const __hip_bfloat16* bg[2];
    void* lA[2];
    void* lB[2];
#pragma unroll
    for (int ii = 0; ii < 2; ++ii) {
        int inst = wave * 2 + ii;
        int ra = m0 + inst * 16 + l4;
        if (ra > M - 1) ra = M - 1;           // clamp (stores are guarded)
        int rb = n0 + inst * 16 + l4;         // Bt rows are padded to tile
        ag[ii] = A + (size_t)ra * Kd + lc;
        bg[ii] = Bt + (size_t)rb * Kd + lc;
        lA[ii] = (char*)As + inst * 1024;
        lB[ii] = (char*)Bs + inst * 1024;
    }

    f32x4 acc[4][4] = {};
    const int q8 = (lane >> 4) * 8;
    const int l15 = lane & 15;

    for (int k0 = 0; k0 < Kd; k0 += 32) {
        glds16(ag[0] + k0, lA[0]);
        glds16(ag[1] + k0, lA[1]);
        glds16(bg[0] + k0, lB[0]);
        glds16(bg[1] + k0, lB[1]);
        __syncthreads();
        short8 af[4], bfr[4];
#pragma unroll
        for (int i = 0; i < 4; ++i) {
            af[i]  = *(const short8*)(As + (size_t)(wm * 64 + i * 16 + l15) * 32 + q8);
            bfr[i] = *(const short8*)(Bs + (size_t)(wn * 64 + i * 16 + l15) * 32 + q8);
        }
#pragma unroll
        for (int i = 0; i < 4; ++i)
#pragma unroll
            for (int j = 0; j < 4; ++j)
                acc[i][j] = __builtin_amdgcn_mfma_f32_16x16x32_bf16(
                    af[i], bfr[j], acc[i][j], 0, 0, 0);
        __syncthreads();
    }

#pragma unroll
    for (int i = 0; i < 4; ++i) {
        int mbase = m0 + wm * 64 + i * 16 + (lane >> 4) * 4;
#pragma unroll
        for (int j = 0; j < 4; ++j) {
            int n = n0 + wn * 64 + j * 16 + l15;
            if (n >= Nreal) continue;
            float bv = bias[n];
#pragma unroll
            for (int r = 0; r < 4; ++r) {
                int m = mbase + r;
                if (m >= M) continue;
                float v = acc[i][j][r] + bv;
                if (EPI == 1) v = v / (1.0f + expf(-v));
                if (EPI == 2) v = fmaxf(v, 0.0f);
                if (EPI == 3) v += rowbias[(size_t)tidx[m] * 1024 + n];
                if (EPI == 0)
                    ((float*)Cout)[(size_t)m * Cstride + n] = v;
                else
                    ((__hip_bfloat16*)Cout)[(size_t)m * Cstride + n] = __float2bfloat16(v);
            }
        }
    }
}

// ----------------------- per-row prep: gumbel argmax + build X[B x 512] bf16
// X = [x_num_t (16) | delta-onehot*69.0776 (384) | zeros (112)]
__global__ __launch_bounds__(256) void prep_x(
    const float* __restrict__ x_num, const int* __restrict__ x_cat,
    const int* __restrict__ t_in, const float* __restrict__ noise,
    const float* __restrict__ gum, const float* __restrict__ sched,
    __hip_bfloat16* __restrict__ X, int* __restrict__ hot) {
    __shared__ float xnt[16][16];
    __shared__ int sh_hot[16][24];
    __shared__ int sh_t[16];
    const int b0 = blockIdx.x * 16;
    const int tid = threadIdx.x;
    const float* LOG_CA = sched + 2000;
    const float* LOG_1M_CA = sched + 3000;
    const float* SQ_AC = sched + 4000;
    const float* SQ_1M = sched + 5000;
    if (tid < 16) sh_t[tid] = t_in[b0 + tid];
    __syncthreads();
    {
        int r = tid >> 4, i = tid & 15;
        int t = sh_t[r];
        xnt[r][i] = SQ_AC[t] * x_num[(size_t)(b0 + r) * 16 + i] +
                    SQ_1M[t] * noise[(size_t)(b0 + r) * 16 + i];
    }
    for (int task = tid; task < 16 * 24; task += 256) {
        int r = task / 24, c = task - r * 24;
        int t = sh_t[r];
        int xc = x_cat[(size_t)(b0 + r) * 24 + c];
        float l1 = LOG_1M_CA[t] - LOGKF;
        float lca = LOG_CA[t];
        float vh = lae(lca, l1);
        float vo = lae(L30F + lca, l1);
        const float* gu = gum + (size_t)(b0 + r) * 384 + c * 16;
        float best = -3.0e38f;
        int bi = 0;
#pragma unroll
        for (int k = 0; k < 16; ++k) {
            float g = -logf(-logf(gu[k] + 1e-30f) + 1e-30f);
            float v = g + ((k == xc) ? vh : vo);
            if (v > best) { best = v; bi = k; }
        }
        sh_hot[r][c] = bi;
        hot[(size_t)(b0 + r) * 24 + c] = bi;
    }
    __syncthreads();
    const float DELTA = 69.07755279f;  // -L30F
#pragma unroll
    for (int it = 0; it < 4; ++it) {
        int e = (it * 256 + tid) << 3;
        int r = e >> 9, j0 = e & 511;
        __hip_bfloat16 v[8];
#pragma unroll
        for (int q = 0; q < 8; ++q) {
            int j = j0 + q;
            float f = 0.0f;
            if (j < 16) {
                f = xnt[r][j];
            } else if (j < 400) {
                int c = (j - 16) >> 4, k = (j - 16) & 15;
                f = (sh_hot[r][c] == k) ? DELTA : 0.0f;
            }
            v[q] = __float2bfloat16(f);
        }
        *(short8*)(X + (size_t)(b0 + r) * 512 + j0) = *(const short8*)v;
    }
}

// ------------------------------------------------------------- reductions
__device__ __forceinline__ void block_reduce_add(double contrib, double* acc_out) {
    for (int off = 32; off > 0; off >>= 1)
        contrib += __shfl_down(contrib, off);
    __shared__ double wsum[4];
    int lane = threadIdx.x & 63, wv = threadIdx.x >> 6;
    if (lane == 0) wsum[wv] = contrib;
    __syncthreads();
    if (threadIdx.x == 0)
        atomicAdd(acc_out, wsum[0] + wsum[1] + wsum[2] + wsum[3]);
}

// one thread per (row, category)
__global__ __launch_bounds__(256) void loss_cat(
    const int* __restrict__ x_cat, const int* __restrict__ t_in,
    const int* __restrict__ hot, const float* __restrict__ MO,
    const float* __restrict__ sched, double* __restrict__ acc_out) {
    int gid = blockIdx.x * 256 + threadIdx.x;
    double contrib = 0.0;
    if (gid < BATCH * NCAT) {
        int b = gid / NCAT, c = gid - b * NCAT;
        int t = t_in[b];
        int xc = x_cat[b * NCAT + c];
        int s = hot[b * NCAT + c];
        const float* LOG_A = sched;
        const float* LOG_1M_A = sched + 1000;
        const float* LOG_CA = sched + 2000;
        const float* LOG_1M_CA = sched + 3000;
        const float* oc = MO + (size_t)b * 400 + 16 + c * 16;
        float ocv[16];
        float mx = -3e38f;
#pragma unroll
        for (int k = 0; k < 16; ++k) { ocv[k] = oc[k]; mx = fmaxf(mx, ocv[k]); }
        float sm = 0.0f;
#pragma unroll
        for (int k = 0; k < 16; ++k) sm += expf(ocv[k] - mx);
        float lse = mx + logf(sm);
        int tm1 = (t > 0) ? t - 1 : 0;
        float lca1 = LOG_CA[tm1];
        float l1m1 = LOG_1M_CA[tm1] - LOGKF;
        float la = LOG_A[t];
        float l1a = LOG_1M_A[t] - LOGKF;
        float qh = lae(la, l1a);
        float qo = lae(L30F + la, l1a);
        float levh = (t == 0) ? 0.0f : lae(lca1, l1m1);
        float levo = (t == 0) ? L30F : lae(L30F + lca1, l1m1);
        float un[16], ut[16];
        float mu = -3e38f, mt2 = -3e38f;
#pragma unroll
        for (int k = 0; k < 16; ++k) {
            float lxh = ocv[k] - lse;
            float lev = (t == 0) ? lxh : lae(lxh + lca1, l1m1);
            float q = (k == s) ? qh : qo;
            un[k] = lev + q;
            ut[k] = ((k == xc) ? levh : levo) + q;
            mu = fmaxf(mu, un[k]);
            mt2 = fmaxf(mt2, ut[k]);
        }
        float su = 0.0f, st = 0.0f;
#pragma unroll
        for (int k = 0; k < 16; ++k) { su += expf(un[k] - mu); st += expf(ut[k] - mt2); }
        float lsu = mu + logf(su), lst = mt2 + logf(st);
        float kl = 0.0f, dn = 0.0f;
#pragma unroll
        for (int k = 0; k < 16; ++k) {
            float lmp = un[k] - lsu;
            float ltp = ut[k] - lst;
            kl += expf(ltp) * (ltp - lmp);
            dn -= ((k == xc) ? 1.0f : 1e-30f) * lmp;
        }
        float Lt = (t == 0) ? dn : kl;
        float lcaT = LOG_CA[999];
        float l1mT = LOG_1M_CA[999] - LOGKF;
        float ph = lae(lcaT, l1mT);
        float po = lae(L30F + lcaT, l1mT);
        float prior = expf(ph) * (ph + LOGKF) + 15.0f * expf(po) * (po + LOGKF);
        contrib = (double)(Lt + prior) / (24.0 * BATCH);
    }
    block_reduce_add(contrib, acc_out);
}

// one thread per (row, numeric-dim)
__global__ __launch_bounds__(256) void loss_gauss(
    const float* __restrict__ noise, const float* __restrict__ MO,
    double* __restrict__ acc_out) {
    int gid = blockIdx.x * 256 + threadIdx.x;
    double contrib = 0.0;
    if (gid < BATCH * 16) {
        int b = gid >> 4, i = gid & 15;
        float d = noise[gid] - MO[(size_t)b * 400 + i];
        contrib = (double)(d * d) / (16.0 * BATCH);
    }
    block_reduce_add(contrib, acc_out);
}

__global__ void finalize_kernel(const double* __restrict__ acc, float* __restrict__ out) {
    out[0] = (float)(*acc);
}

extern "C" void kernel_launch(void* const* d_in, const int* in_sizes, int n_in,
                              void* d_out, int out_size, void* d_ws, size_t ws_size,
                              hipStream_t stream) {
    const float* x_num  = (const float*)d_in[0];
    const int*   x_cat  = (const int*)d_in[1];
    const int*   t_in   = (const int*)d_in[2];
    const float* noise  = (const float*)d_in[3];
    const float* gum    = (const float*)d_in[4];
    const float* te_w1  = (const float*)d_in[5];
    const float* te_b1  = (const float*)d_in[6];
    const float* te_w2  = (const float*)d_in[7];
    const float* te_b2  = (const float*)d_in[8];
    const float* proj_w = (const float*)d_in[9];
    const float* proj_b = (const float*)d_in[10];
    const float* mlp_w1 = (const float*)d_in[11];
    const float* mlp_b1 = (const float*)d_in[12];
    const float* mlp_w2 = (const float*)d_in[13];
    const float* mlp_b2 = (const float*)d_in[14];
    float* out = (float*)d_out;

    char* w = (char*)d_ws;
    size_t off = 0;
    auto alloc = [&](size_t bytes) {
        void* p = w + off;
        off += (bytes + 1023) & ~(size_t)1023;
        return p;
    };
    double* acc     = (double*)alloc(1024);
    float* sched    = (float*)alloc(6 * 1000 * 4);
    int*   hot      = (int*)alloc((size_t)BATCH * 24 * 4);
    float* colconst = (float*)alloc(1024 * 4);
    __hip_bfloat16* E0   = (__hip_bfloat16*)alloc((size_t)1000 * 1024 * 2);
    __hip_bfloat16* E1   = (__hip_bfloat16*)alloc((size_t)1000 * 1024 * 2);
    float* EMB           = (float*)alloc((size_t)1000 * 1024 * 4);
    __hip_bfloat16* tw1t = (__hip_bfloat16*)alloc((size_t)1024 * 1024 * 2);
    __hip_bfloat16* tw2t = (__hip_bfloat16*)alloc((size_t)1024 * 1024 * 2);
    __hip_bfloat16* pwt  = (__hip_bfloat16*)alloc((size_t)1024 * 512 * 2);
    __hip_bfloat16* w1t  = (__hip_bfloat16*)alloc((size_t)1024 * 1024 * 2);
    __hip_bfloat16* w2t  = (__hip_bfloat16*)alloc((size_t)512 * 1024 * 2);
    __hip_bfloat16* X    = (__hip_bfloat16*)alloc((size_t)BATCH * 512 * 2);
    __hip_bfloat16* h    = (__hip_bfloat16*)alloc((size_t)BATCH * 1024 * 2);
    __hip_bfloat16* R    = (__hip_bfloat16*)alloc((size_t)BATCH * 1024 * 2);
    float* MO            = (float*)alloc((size_t)BATCH * 400 * 4);

    sched_kernel<<<1, 256, 0, stream>>>(sched, acc);
    emb0_kernel<<<4000, 256, 0, stream>>>(E0);
    colconst_kernel<<<4, 256, 0, stream>>>(proj_w, proj_b, colconst);
    // weight transposes + bf16 convert
    wtrans_kernel<<<dim3(32, 32), 256, 0, stream>>>(te_w1, tw1t, 1024, 1024, 1024, 1024);
    wtrans_kernel<<<dim3(32, 32), 256, 0, stream>>>(te_w2, tw2t, 1024, 1024, 1024, 1024);
    wtrans_kernel<<<dim3(32, 16), 256, 0, stream>>>(proj_w, pwt, 400, 512, 1024, 1024);
    wtrans_kernel<<<dim3(32, 32), 256, 0, stream>>>(mlp_w1, w1t, 1024, 1024, 1024, 1024);
    wtrans_kernel<<<dim3(16, 32), 256, 0, stream>>>(mlp_w2, w2t, 1024, 1024, 400, 512);
    // E1 = silu(E0 @ te_w1 + te_b1)   [bf16 out]
    gemm_mfma<1><<<dim3(8, 8), 256, 0, stream>>>(E0, tw1t, te_b1, E1, 1000, 1024, 1024, 1024, nullptr, nullptr);
    // EMB = E1 @ te_w2 + te_b2        [f32 out]
    gemm_mfma<0><<<dim3(8, 8), 256, 0, stream>>>(E1, tw2t, te_b2, EMB, 1000, 1024, 1024, 1024, nullptr, nullptr);
    // X + hot
    prep_x<<<BATCH / 16, 256, 0, stream>>>(x_num, x_cat, t_in, noise, gum, sched, X, hot);
    // h = X @ proj_w^T + colconst + EMB[t]   [bf16 out]
    gemm_mfma<3><<<dim3(8, 128), 256, 0, stream>>>(X, pwt, colconst, h, BATCH, 512, 1024, 1024, t_in, EMB);
    // R = relu(h @ mlp_w1 + mlp_b1)   [bf16 out]
    gemm_mfma<2><<<dim3(8, 128), 256, 0, stream>>>(h, w1t, mlp_b1, R, BATCH, 1024, 1024, 1024, nullptr, nullptr);
    // MO = R @ mlp_w2 + mlp_b2        [f32 out, N=400]
    gemm_mfma<0><<<dim3(4, 128), 256, 0, stream>>>(R, w2t, mlp_b2, MO, BATCH, 1024, 400, 400, nullptr, nullptr);
    loss_cat<<<(BATCH * NCAT) / 256, 256, 0, stream>>>(x_cat, t_in, hot, MO, sched, acc);
    loss_gauss<<<(BATCH * 16) / 256, 256, 0, stream>>>(noise, MO, acc);
    finalize_kernel<<<1, 1, 0, stream>>>(acc, out);
}

// Round 4
// 390.087 us; speedup vs baseline: 2.8090x; 1.1989x over previous
//
#include <hip/hip_runtime.h>
#include <hip/hip_bf16.h>
#include <math.h>

#define BATCH 16384
#define NCAT 24

// log(1e-30f), log(16)
#define L30F  (-69.07755279f)
#define LOGKF (2.7725887f)

typedef __attribute__((ext_vector_type(8))) short short8;
typedef __attribute__((ext_vector_type(4))) float f32x4;

__device__ __forceinline__ float lae(float a, float b) {
    float m = fmaxf(a, b);
    return m + logf(expf(a - m) + expf(b - m));
}

__device__ __forceinline__ void glds16(const void* g, void* l) {
    __builtin_amdgcn_global_load_lds((const __attribute__((address_space(1))) void*)g,
                                     (__attribute__((address_space(3))) void*)l,
                                     16, 0, 0);
}

// --------------------------------------- fused setup: emb0 + colconst + sched
// blocks [0,4000): E0 bf16 timestep-embedding table (1000x1024, t<1024 padded ok)
// blocks [4000,4004): colconst[j] = proj_b[j] + L30F * sum_{r=16}^{399} proj_w[r][j]
// block 4004: schedules
__global__ __launch_bounds__(256) void setup_kernel(
    __hip_bfloat16* __restrict__ E0, const float* __restrict__ proj_w,
    const float* __restrict__ proj_b, float* __restrict__ colconst,
    float* __restrict__ sched, double* __restrict__ acc) {
    const int bid = blockIdx.x, tid = threadIdx.x;
    if (bid < 4000) {
        int gid = bid * 256 + tid;
        int t = gid >> 10, j = gid & 1023;
        int jj = (j < 512) ? j : j - 512;
        float freq = expf(-logf(10000.0f) * (float)jj / 512.0f);
        float arg = (float)t * freq;
        E0[gid] = __float2bfloat16((j < 512) ? cosf(arg) : sinf(arg));
    } else if (bid < 4004) {
        int j = (bid - 4000) * 256 + tid;
        float s = 0.0f;
        for (int r = 16; r < 400; ++r) s += proj_w[(size_t)r * 1024 + j];
        colconst[j] = proj_b[j] + L30F * s;
    } else {
        __shared__ double la_s[1000];
        __shared__ double lca_s[1000];
        const double PI = 3.14159265358979323846;
        for (int i = tid; i < 1000; i += 256) {
            double u0 = ((double)i / 1000.0 + 0.008) / 1.008 * PI * 0.5;
            double u1 = ((double)(i + 1) / 1000.0 + 0.008) / 1.008 * PI * 0.5;
            double c0 = cos(u0), c1 = cos(u1);
            double beta = 1.0 - (c1 * c1) / (c0 * c0);
            if (beta > 0.999) beta = 0.999;
            la_s[i] = log(1.0 - beta);
        }
        __syncthreads();
        if (tid == 0) {
            double run = 0.0;
            for (int i = 0; i < 1000; ++i) { run += la_s[i]; lca_s[i] = run; }
            *acc = 0.0;
        }
        __syncthreads();
        for (int i = tid; i < 1000; i += 256) {
            double la = la_s[i], lca = lca_s[i];
            sched[i]        = (float)la;
            sched[1000 + i] = (float)log(1.0 - exp(la) + 1e-40);
            sched[2000 + i] = (float)lca;
            sched[3000 + i] = (float)log(1.0 - exp(lca) + 1e-40);
            sched[4000 + i] = (float)sqrt(exp(lca));
            sched[5000 + i] = (float)sqrt(1.0 - exp(lca));
        }
    }
}

// --------------------------- fused weight transpose + f32->bf16 (all 5 weights)
// job j: W[K x Nw] f32 -> Wt[Npad x Kpad] bf16 (zero-filled pad)
__global__ __launch_bounds__(256) void wtrans5_kernel(
    const float* __restrict__ s0, const float* __restrict__ s1,
    const float* __restrict__ s2, const float* __restrict__ s3,
    const float* __restrict__ s4,
    __hip_bfloat16* __restrict__ d0, __hip_bfloat16* __restrict__ d1,
    __hip_bfloat16* __restrict__ d2, __hip_bfloat16* __restrict__ d3,
    __hip_bfloat16* __restrict__ d4) {
    // job table: {block_off, nx, K, Kpad, Nw, Npad}
    const int boff[6] = {0, 1024, 2048, 2560, 3584, 4096};
    const int nxs[5]  = {32, 32, 32, 32, 16};
    const int Ks[5]   = {1024, 1024, 400, 1024, 1024};
    const int Kps[5]  = {1024, 1024, 512, 1024, 1024};
    const int Nws[5]  = {1024, 1024, 1024, 1024, 400};
    const int Nps[5]  = {1024, 1024, 1024, 1024, 512};
    const int bid = blockIdx.x;
    int job = 0;
#pragma unroll
    for (int j = 1; j < 5; ++j) job += (bid >= boff[j]) ? 1 : 0;
    const float* W = (job == 0) ? s0 : (job == 1) ? s1 : (job == 2) ? s2 : (job == 3) ? s3 : s4;
    __hip_bfloat16* Wt = (job == 0) ? d0 : (job == 1) ? d1 : (job == 2) ? d2 : (job == 3) ? d3 : d4;
    const int lb = bid - boff[job];
    const int K = Ks[job], Kpad = Kps[job], Nw = Nws[job], Npad = Nps[job];
    const int n0 = (lb % nxs[job]) * 32, k0 = (lb / nxs[job]) * 32;
    __shared__ float t[32][33];
    int c = threadIdx.x & 31, r8 = threadIdx.x >> 5;
#pragma unroll
    for (int i = 0; i < 32; i += 8) {
        int k = k0 + r8 + i, n = n0 + c;
        t[r8 + i][c] = (n < Nw && k < K) ? W[(size_t)k * Nw + n] : 0.0f;
    }
    __syncthreads();
#pragma unroll
    for (int i = 0; i < 32; i += 8) {
        int n = n0 + r8 + i, k = k0 + c;
        if (n < Npad && k < Kpad) Wt[(size_t)n * Kpad + k] = __float2bfloat16(t[c][r8 + i]);
    }
}

// ------------------------------------------------------------ bf16 MFMA GEMM
// C[M,Nreal] = epi(A[M,Kd] @ Bt^T + bias), A row-major bf16, Bt [Npad x Kd] bf16.
// TILE x TILE block tile, BK=64 (two 32-wide LDS sub-tiles), 4 waves (2x2).
// XCD-aware swizzle: same-m n-blocks consecutive within one XCD.
// EPI: 0 = f32 store, 1 = silu + bf16, 2 = relu + bf16, 3 = +rowbias[tidx[m]] + bf16
template <int EPI, int TILE>
__global__ __launch_bounds__(256) void gemm_mfma(
    const __hip_bfloat16* __restrict__ A, const __hip_bfloat16* __restrict__ Bt,
    const float* __restrict__ bias, void* __restrict__ Cout,
    int M, int Kd, int Nreal, int Cstride,
    const int* __restrict__ tidx, const float* __restrict__ rowbias) {
    constexpr int FM  = TILE / 32;   // MFMA frags per wave per dim
    constexpr int CPH = TILE / 16;   // staging chunks per 32-wide half (per matrix)
    constexpr int CPM = TILE / 8;    // chunks per matrix (2 halves)
    constexpr int CPW = TILE / 16;   // chunks per wave (2*CPM/4)
    __shared__ __hip_bfloat16 LDS[4 * TILE * 32];
    __hip_bfloat16* As = LDS;                   // [2][TILE][32]
    __hip_bfloat16* Bs = LDS + 2 * TILE * 32;   // [2][TILE][32]

    const int tid = threadIdx.x;
    const int lane = tid & 63, wave = tid >> 6;
    const int wm = wave >> 1, wn = wave & 1;

    // XCD swizzle (blocks dispatched x-fastest; XCD = linear_id % 8 heuristic)
    int mb, nb;
    {
        int nbx = gridDim.x, nby = gridDim.y;
        int b = blockIdx.y * nbx + blockIdx.x;
        if ((nby & 7) == 0) {
            int x = b & 7, g = b >> 3;
            nb = g % nbx;
            mb = x + 8 * (g / nbx);
        } else { mb = blockIdx.y; nb = blockIdx.x; }
    }
    const int m0 = mb * TILE, n0 = nb * TILE;

    const int l16r = lane >> 2;        // row within 16-row chunk
    const int l16c = (lane & 3) * 8;   // element col within 32-wide half

    const __hip_bfloat16* gsrc[CPW];
    char* ldst[CPW];
#pragma unroll
    for (int i = 0; i < CPW; ++i) {
        int gc = wave * CPW + i;
        int mat = gc / CPM, rem = gc % CPM;
        int half = rem / CPH, rb = rem % CPH;
        int row = rb * 16 + l16r;
        size_t ldsoff = (size_t)(half * TILE * 32 + rb * 16 * 32) * 2;
        if (mat == 0) {
            int r = m0 + row; if (r > M - 1) r = M - 1;   // clamp; stores guarded
            gsrc[i] = A + (size_t)r * Kd + half * 32 + l16c;
            ldst[i] = (char*)As + ldsoff;
        } else {
            int r = n0 + row;                             // Bt padded to tile
            gsrc[i] = Bt + (size_t)r * Kd + half * 32 + l16c;
            ldst[i] = (char*)Bs + ldsoff;
        }
    }

    f32x4 acc[FM][FM] = {};
    const int q8 = (lane >> 4) * 8;
    const int l15 = lane & 15;

    for (int k0 = 0; k0 < Kd; k0 += 64) {
#pragma unroll
        for (int i = 0; i < CPW; ++i) glds16(gsrc[i] + k0, ldst[i]);
        __syncthreads();
#pragma unroll
        for (int kk = 0; kk < 2; ++kk) {
            short8 af[FM], bfr[FM];
#pragma unroll
            for (int i = 0; i < FM; ++i) {
                af[i]  = *(const short8*)(As + kk * TILE * 32 +
                                          (wm * (TILE / 2) + i * 16 + l15) * 32 + q8);
                bfr[i] = *(const short8*)(Bs + kk * TILE * 32 +
                                          (wn * (TILE / 2) + i * 16 + l15) * 32 + q8);
            }
#pragma unroll
            for (int i = 0; i < FM; ++i)
#pragma unroll
                for (int j = 0; j < FM; ++j)
                    acc[i][j] = __builtin_amdgcn_mfma_f32_16x16x32_bf16(
                        af[i], bfr[j], acc[i][j], 0, 0, 0);
        }
        __syncthreads();
    }

#pragma unroll
    for (int i = 0; i < FM; ++i) {
        int mbase = m0 + wm * (TILE / 2) + i * 16 + (lane >> 4) * 4;
#pragma unroll
        for (int j = 0; j < FM; ++j) {
            int n = n0 + wn * (TILE / 2) + j * 16 + l15;
            if (n >= Nreal) continue;
            float bv = bias[n];
#pragma unroll
            for (int r = 0; r < 4; ++r) {
                int m = mbase + r;
                if (m >= M) continue;
                float v = acc[i][j][r] + bv;
                if (EPI == 1) v = v / (1.0f + expf(-v));
                if (EPI == 2) v = fmaxf(v, 0.0f);
                if (EPI == 3) v += rowbias[(size_t)tidx[m] * 1024 + n];
                if (EPI == 0)
                    ((float*)Cout)[(size_t)m * Cstride + n] = v;
                else
                    ((__hip_bfloat16*)Cout)[(size_t)m * Cstride + n] = __float2bfloat16(v);
            }
        }
    }
}

// ----------------------- per-row prep: gumbel argmax + build X[B x 512] bf16
// X = [x_num_t (16) | delta-onehot*69.0776 (384) | zeros (112)]
__global__ __launch_bounds__(256) void prep_x(
    const float* __restrict__ x_num, const int* __restrict__ x_cat,
    const int* __restrict__ t_in, const float* __restrict__ noise,
    const float* __restrict__ gum, const float* __restrict__ sched,
    __hip_bfloat16* __restrict__ X, int* __restrict__ hot) {
    __shared__ float xnt[16][16];
    __shared__ int sh_hot[16][24];
    __shared__ int sh_t[16];
    const int b0 = blockIdx.x * 16;
    const int tid = threadIdx.x;
    const float* LOG_CA = sched + 2000;
    const float* LOG_1M_CA = sched + 3000;
    const float* SQ_AC = sched + 4000;
    const float* SQ_1M = sched + 5000;
    if (tid < 16) sh_t[tid] = t_in[b0 + tid];
    __syncthreads();
    {
        int r = tid >> 4, i = tid & 15;
        int t = sh_t[r];
        xnt[r][i] = SQ_AC[t] * x_num[(size_t)(b0 + r) * 16 + i] +
                    SQ_1M[t] * noise[(size_t)(b0 + r) * 16 + i];
    }
    for (int task = tid; task < 16 * 24; task += 256) {
        int r = task / 24, c = task - r * 24;
        int t = sh_t[r];
        int xc = x_cat[(size_t)(b0 + r) * 24 + c];
        float l1 = LOG_1M_CA[t] - LOGKF;
        float lca = LOG_CA[t];
        float vh = lae(lca, l1);
        float vo = lae(L30F + lca, l1);
        const float* gu = gum + (size_t)(b0 + r) * 384 + c * 16;
        float best = -3.0e38f;
        int bi = 0;
#pragma unroll
        for (int k = 0; k < 16; ++k) {
            float g = -logf(-logf(gu[k] + 1e-30f) + 1e-30f);
            float v = g + ((k == xc) ? vh : vo);
            if (v > best) { best = v; bi = k; }
        }
        sh_hot[r][c] = bi;
        hot[(size_t)(b0 + r) * 24 + c] = bi;
    }
    __syncthreads();
    const float DELTA = 69.07755279f;  // -L30F
#pragma unroll
    for (int it = 0; it < 4; ++it) {
        int e = (it * 256 + tid) << 3;
        int r = e >> 9, j0 = e & 511;
        __hip_bfloat16 v[8];
#pragma unroll
        for (int q = 0; q < 8; ++q) {
            int j = j0 + q;
            float f = 0.0f;
            if (j < 16) {
                f = xnt[r][j];
            } else if (j < 400) {
                int c = (j - 16) >> 4, k = (j - 16) & 15;
                f = (sh_hot[r][c] == k) ? DELTA : 0.0f;
            }
            v[q] = __float2bfloat16(f);
        }
        *(short8*)(X + (size_t)(b0 + r) * 512 + j0) = *(const short8*)v;
    }
}

// ------------------------------------------------------------- reductions
__device__ __forceinline__ void block_reduce_add(double contrib, double* acc_out) {
    for (int off = 32; off > 0; off >>= 1)
        contrib += __shfl_down(contrib, off);
    __shared__ double wsum[4];
    int lane = threadIdx.x & 63, wv = threadIdx.x >> 6;
    if (lane == 0) wsum[wv] = contrib;
    __syncthreads();
    if (threadIdx.x == 0)
        atomicAdd(acc_out, wsum[0] + wsum[1] + wsum[2] + wsum[3]);
}

// fused loss: gid < B*24 -> categorical term; else gaussian term
__global__ __launch_bounds__(256) void loss_kernel(
    const int* __restrict__ x_cat, const int* __restrict__ t_in,
    const int* __restrict__ hot, const float* __restrict__ MO,
    const float* __restrict__ noise, const float* __restrict__ sched,
    double* __restrict__ acc_out) {
    int gid = blockIdx.x * 256 + threadIdx.x;
    double contrib = 0.0;
    if (gid < BATCH * NCAT) {
        int b = gid / NCAT, c = gid - b * NCAT;
        int t = t_in[b];
        int xc = x_cat[b * NCAT + c];
        int s = hot[b * NCAT + c];
        const float* LOG_A = sched;
        const float* LOG_1M_A = sched + 1000;
        const float* LOG_CA = sched + 2000;
        const float* LOG_1M_CA = sched + 3000;
        const float* oc = MO + (size_t)b * 400 + 16 + c * 16;
        float ocv[16];
        float mx = -3e38f;
#pragma unroll
        for (int k = 0; k < 16; ++k) { ocv[k] = oc[k]; mx = fmaxf(mx, ocv[k]); }
        float sm = 0.0f;
#pragma unroll
        for (int k = 0; k < 16; ++k) sm += expf(ocv[k] - mx);
        float lse = mx + logf(sm);
        int tm1 = (t > 0) ? t - 1 : 0;
        float lca1 = LOG_CA[tm1];
        float l1m1 = LOG_1M_CA[tm1] - LOGKF;
        float la = LOG_A[t];
        float l1a = LOG_1M_A[t] - LOGKF;
        float qh = lae(la, l1a);
        float qo = lae(L30F + la, l1a);
        float levh = (t == 0) ? 0.0f : lae(lca1, l1m1);
        float levo = (t == 0) ? L30F : lae(L30F + lca1, l1m1);
        float un[16], ut[16];
        float mu = -3e38f, mt2 = -3e38f;
#pragma unroll
        for (int k = 0; k < 16; ++k) {
            float lxh = ocv[k] - lse;
            float lev = (t == 0) ? lxh : lae(lxh + lca1, l1m1);
            float q = (k == s) ? qh : qo;
            un[k] = lev + q;
            ut[k] = ((k == xc) ? levh : levo) + q;
            mu = fmaxf(mu, un[k]);
            mt2 = fmaxf(mt2, ut[k]);
        }
        float su = 0.0f, st = 0.0f;
#pragma unroll
        for (int k = 0; k < 16; ++k) { su += expf(un[k] - mu); st += expf(ut[k] - mt2); }
        float lsu = mu + logf(su), lst = mt2 + logf(st);
        float kl = 0.0f, dn = 0.0f;
#pragma unroll
        for (int k = 0; k < 16; ++k) {
            float lmp = un[k] - lsu;
            float ltp = ut[k] - lst;
            kl += expf(ltp) * (ltp - lmp);
            dn -= ((k == xc) ? 1.0f : 1e-30f) * lmp;
        }
        float Lt = (t == 0) ? dn : kl;
        float lcaT = LOG_CA[999];
        float l1mT = LOG_1M_CA[999] - LOGKF;
        float ph = lae(lcaT, l1mT);
        float po = lae(L30F + lcaT, l1mT);
        float prior = expf(ph) * (ph + LOGKF) + 15.0f * expf(po) * (po + LOGKF);
        contrib = (double)(Lt + prior) / (24.0 * BATCH);
    } else if (gid < BATCH * (NCAT + 16)) {
        int g2 = gid - BATCH * NCAT;
        int b = g2 >> 4, i = g2 & 15;
        float d = noise[g2] - MO[(size_t)b * 400 + i];
        contrib = (double)(d * d) / (16.0 * BATCH);
    }
    block_reduce_add(contrib, acc_out);
}

__global__ void finalize_kernel(const double* __restrict__ acc, float* __restrict__ out) {
    out[0] = (float)(*acc);
}

extern "C" void kernel_launch(void* const* d_in, const int* in_sizes, int n_in,
                              void* d_out, int out_size, void* d_ws, size_t ws_size,
                              hipStream_t stream) {
    const float* x_num  = (const float*)d_in[0];
    const int*   x_cat  = (const int*)d_in[1];
    const int*   t_in   = (const int*)d_in[2];
    const float* noise  = (const float*)d_in[3];
    const float* gum    = (const float*)d_in[4];
    const float* te_w1  = (const float*)d_in[5];
    const float* te_b1  = (const float*)d_in[6];
    const float* te_w2  = (const float*)d_in[7];
    const float* te_b2  = (const float*)d_in[8];
    const float* proj_w = (const float*)d_in[9];
    const float* proj_b = (const float*)d_in[10];
    const float* mlp_w1 = (const float*)d_in[11];
    const float* mlp_b1 = (const float*)d_in[12];
    const float* mlp_w2 = (const float*)d_in[13];
    const float* mlp_b2 = (const float*)d_in[14];
    float* out = (float*)d_out;

    char* w = (char*)d_ws;
    size_t off = 0;
    auto alloc = [&](size_t bytes) {
        void* p = w + off;
        off += (bytes + 1023) & ~(size_t)1023;
        return p;
    };
    double* acc     = (double*)alloc(1024);
    float* sched    = (float*)alloc(6 * 1000 * 4);
    int*   hot      = (int*)alloc((size_t)BATCH * 24 * 4);
    float* colconst = (float*)alloc(1024 * 4);
    __hip_bfloat16* E0   = (__hip_bfloat16*)alloc((size_t)1024 * 1024 * 2);
    __hip_bfloat16* E1   = (__hip_bfloat16*)alloc((size_t)1024 * 1024 * 2);
    float* EMB           = (float*)alloc((size_t)1000 * 1024 * 4);
    __hip_bfloat16* tw1t = (__hip_bfloat16*)alloc((size_t)1024 * 1024 * 2);
    __hip_bfloat16* tw2t = (__hip_bfloat16*)alloc((size_t)1024 * 1024 * 2);
    __hip_bfloat16* pwt  = (__hip_bfloat16*)alloc((size_t)1024 * 512 * 2);
    __hip_bfloat16* w1t  = (__hip_bfloat16*)alloc((size_t)1024 * 1024 * 2);
    __hip_bfloat16* w2t  = (__hip_bfloat16*)alloc((size_t)512 * 1024 * 2);
    __hip_bfloat16* X    = (__hip_bfloat16*)alloc((size_t)BATCH * 512 * 2);
    __hip_bfloat16* h    = (__hip_bfloat16*)alloc((size_t)BATCH * 1024 * 2);
    __hip_bfloat16* R    = (__hip_bfloat16*)alloc((size_t)BATCH * 1024 * 2);
    float* MO            = (float*)alloc((size_t)BATCH * 400 * 4);

    // setup: E0 table + colconst + schedules (one launch)
    setup_kernel<<<4005, 256, 0, stream>>>(E0, proj_w, proj_b, colconst, sched, acc);
    // all 5 weight transposes (one launch)
    wtrans5_kernel<<<4096, 256, 0, stream>>>(te_w1, te_w2, proj_w, mlp_w1, mlp_w2,
                                             tw1t, tw2t, pwt, w1t, w2t);
    // E1 = silu(E0 @ te_w1 + te_b1)   [bf16 out, 64-tile for occupancy]
    gemm_mfma<1, 64><<<dim3(16, 16), 256, 0, stream>>>(E0, tw1t, te_b1, E1, 1000, 1024, 1024, 1024, nullptr, nullptr);
    // EMB = E1 @ te_w2 + te_b2        [f32 out]
    gemm_mfma<0, 64><<<dim3(16, 16), 256, 0, stream>>>(E1, tw2t, te_b2, EMB, 1000, 1024, 1024, 1024, nullptr, nullptr);
    // X + hot
    prep_x<<<BATCH / 16, 256, 0, stream>>>(x_num, x_cat, t_in, noise, gum, sched, X, hot);
    // h = X @ proj_w^T + colconst + EMB[t]   [bf16 out]
    gemm_mfma<3, 128><<<dim3(8, 128), 256, 0, stream>>>(X, pwt, colconst, h, BATCH, 512, 1024, 1024, t_in, EMB);
    // R = relu(h @ mlp_w1 + mlp_b1)   [bf16 out]
    gemm_mfma<2, 128><<<dim3(8, 128), 256, 0, stream>>>(h, w1t, mlp_b1, R, BATCH, 1024, 1024, 1024, nullptr, nullptr);
    // MO = R @ mlp_w2 + mlp_b2        [f32 out, N=400]
    gemm_mfma<0, 128><<<dim3(4, 128), 256, 0, stream>>>(R, w2t, mlp_b2, MO, BATCH, 1024, 400, 400, nullptr, nullptr);
    // fused loss (cat + gauss)
    loss_kernel<<<(BATCH * (NCAT + 16)) / 256, 256, 0, stream>>>(x_cat, t_in, hot, MO, noise, sched, acc);
    finalize_kernel<<<1, 1, 0, stream>>>(acc, out);
}